// Round 1
// baseline (758.706 us; speedup 1.0000x reference)
//
#include <hip/hip_runtime.h>

// VectorQuantizer: z (8,64,16,64,64) f32, emb (512,64) f32.
// N = 524288, D = 64, K = 512.
// out flat = [ z_q_st (33554432 f32) | loss (1 f32) | indices (524288 f32) ]
//
// Bit-exact replication of the checker's np fp32 arithmetic (verified R3):
//   d[n,k] = fl( fmaf(-2, M_nk, zz_n) + ee_k ),  M_nk = sequential fma chain
//   c=0..63; zz/ee = numpy pairwise sum-of-squares (n=64 pattern);
//   argmin = strict <, ascending k.
//
// R6: the R5 "fix" never landed — rocprof showed VGPR_Count=48, but zr[64]
// needs 64 VGPRs, so the allocator was STILL demoting the z-row (AGPR
// shuttle / reload) to chase the 8-waves/EU occupancy tier (<=64 VGPRs).
// VALU-busy time was 523us vs the 218us pure-FMA floor => ~2.4x instruction
// bloat in the k-loop. __launch_bounds__(256,4) only sets MIN waves/EU; the
// allocator still minimizes registers toward max occupancy. The actual knob
// is amdgpu_waves_per_eu(min,max): max=4 caps the occupancy target, giving a
// 128-VGPR budget so zr[64] stays resident and the inner loop is the pure
// v_fmac(v_m, s_e, v_z) chain. 4 waves/SIMD still saturates the 4-cyc
// dependent-FMA latency (needs 2) with slack for scalar-cache misses.

#define NK       512
#define DD       64
#define LOSS_OFF 33554432
#define IDX_OFF  33554433
#define EE_FOFF  4            // float offset of ee[512] in ws (byte 16)

typedef float f32x4 __attribute__((ext_vector_type(4)));
#define CONST_AS __attribute__((address_space(4)))

// numpy pairwise_sum of squares, n=64: 8 strided accumulators combined
// ((r0+r1)+(r2+r3))+((r4+r5)+(r6+r7)); squares rounded separately (asm
// barrier blocks -ffp-contract=fast from fusing square into add).
__device__ __forceinline__ float np_sumsq64(const float* v) {
    float r[8];
    #pragma unroll
    for (int j = 0; j < 8; ++j) {
        float s = v[j] * v[j];
        asm volatile("" : "+v"(s));
        r[j] = s;
    }
    #pragma unroll
    for (int i = 8; i < 64; i += 8) {
        #pragma unroll
        for (int j = 0; j < 8; ++j) {
            float s = v[i + j] * v[i + j];
            asm volatile("" : "+v"(s));
            r[j] += s;
        }
    }
    return ((r[0] + r[1]) + (r[2] + r[3])) + ((r[4] + r[5]) + (r[6] + r[7]));
}

__global__ void vq_ee(const float* __restrict__ emb, float* __restrict__ ws) {
    const int k = blockIdx.x * 256 + threadIdx.x;      // grid 2 x 256
    float row[DD];
    const float* er = emb + k * DD;
    #pragma unroll
    for (int c = 0; c < DD; ++c) row[c] = er[c];
    ws[EE_FOFF + k] = np_sumsq64(row);
}

__global__ __launch_bounds__(256)
__attribute__((amdgpu_waves_per_eu(3, 4)))
void vq_main(const float* __restrict__ z, const float* __restrict__ emb,
             float* __restrict__ out, float* __restrict__ ws) {
    const int n  = blockIdx.x * 256 + threadIdx.x;     // grid 2048 x 256
    const int b  = n >> 16;
    const int sp = n & 65535;
    const float* zp = z + ((size_t)b << 22) + sp;

    float zr[DD];                                      // 64 VGPRs, pinned
    #pragma unroll
    for (int c = 0; c < DD; ++c) zr[c] = zp[(size_t)c << 16];
    const float zz = np_sumsq64(zr);
    #pragma unroll
    for (int c = 0; c < DD; ++c) asm volatile("" : "+v"(zr[c]));

    // constant-address-space views -> s_load (scalar cache, SGPR destinations)
    const CONST_AS f32x4* e4  = (const CONST_AS f32x4*)emb;            // 16/row
    const CONST_AS float* eec = (const CONST_AS float*)(ws + EE_FOFF);

    float best = 3.4e38f;
    int   bi   = 0;

    #pragma unroll 1
    for (int k = 0; k < NK; ++k) {
        const CONST_AS f32x4* er = e4 + (k << 4);      // uniform address
        float m = 0.f;                                 // THE sequential chain
        #pragma unroll
        for (int c4 = 0; c4 < 16; ++c4) {
            const f32x4 e = er[c4];                    // s_load_dwordx4/x16
            m = fmaf(zr[c4 * 4 + 0], e.x, m);
            m = fmaf(zr[c4 * 4 + 1], e.y, m);
            m = fmaf(zr[c4 * 4 + 2], e.z, m);
            m = fmaf(zr[c4 * 4 + 3], e.w, m);
        }
        const float d = fmaf(-2.f, m, zz) + eec[k];
        if (d < best) { best = d; bi = k; }            // strict <, ascending k
    }

    // epilogue: gather z_q row (emb L1/L2-hot, divergent bi), coalesced writes
    float* op = out + ((size_t)b << 22) + sp;
    const float4* brow = (const float4*)(emb + bi * DD);
    float lsum = 0.f;
    #pragma unroll
    for (int c4 = 0; c4 < 16; ++c4) {
        float4 e = brow[c4];
        float eq[4] = { e.x, e.y, e.z, e.w };
        #pragma unroll
        for (int j = 0; j < 4; ++j) {
            const int c = c4 * 4 + j;
            float d = eq[j] - zr[c];
            lsum = fmaf(d, d, lsum);
            op[(size_t)c << 16] = eq[j];
        }
    }
    out[IDX_OFF + n] = (float)bi;

    #pragma unroll
    for (int off = 32; off > 0; off >>= 1) lsum += __shfl_down(lsum, off);
    if ((threadIdx.x & 63) == 0)
        atomicAdd((double*)ws, (double)lsum);          // fp64 final accumulation

    asm volatile("" :: "v"(zr[0]));                    // keep pins honest
}

__global__ void vq_finalize(const float* __restrict__ ws, float* __restrict__ out) {
    out[LOSS_OFF] = (float)(((const double*)ws)[0] * (1.25 / 33554432.0));
}

extern "C" void kernel_launch(void* const* d_in, const int* in_sizes, int n_in,
                              void* d_out, int out_size, void* d_ws, size_t ws_size,
                              hipStream_t stream) {
    const float* z   = (const float*)d_in[0];
    const float* emb = (const float*)d_in[1];
    float* out = (float*)d_out;
    float* ws  = (float*)d_ws;

    hipMemsetAsync(d_ws, 0, 16, stream);               // zero fp64 loss accumulator
    vq_ee<<<dim3(2), dim3(256), 0, stream>>>(emb, ws);
    vq_main<<<dim3(2048), dim3(256), 0, stream>>>(z, emb, out, ws);
    vq_finalize<<<dim3(1), dim3(1), 0, stream>>>(ws, out);
}